// Round 21
// baseline (442.638 us; speedup 1.0000x reference)
//
#include <hip/hip_runtime.h>
#include <math.h>

#define B_ 4
#define S_ 2048
#define D_ 1024
#define F_ 4096
#define E_ 4
#define T_ (B_*S_)        // 8192 tokens
#define PCAP_ 9216        // max padded rows (256-pad per expert)
#define GCAP_ (PCAP_/16)  // 576 row-groups
#define MB128_ (PCAP_/128) // 72 global m-blocks at 128-row tiles

typedef unsigned short ushort_t;
typedef __attribute__((ext_vector_type(8))) short short8;
typedef __attribute__((ext_vector_type(4))) float f32x4;

__device__ __forceinline__ ushort_t f2bf_rne(float f) {
    unsigned u = __float_as_uint(f);
    unsigned r = 0x7FFFu + ((u >> 16) & 1u);
    u += r;
    return (ushort_t)(u >> 16);
}

__device__ __forceinline__ void gload16(const void* g, void* l) {
    __builtin_amdgcn_global_load_lds(
        (const __attribute__((address_space(1))) unsigned int*)g,
        (__attribute__((address_space(3))) unsigned int*)l, 16, 0, 0);
}

// ---------------- routing ----------------

__global__ void k_router(const float* __restrict__ x, const float* __restrict__ rw,
                         float* __restrict__ r, int* __restrict__ counts) {
    if (blockIdx.x == 0 && threadIdx.x < E_) counts[threadIdx.x] = 0;
    int wid = blockIdx.x * 4 + (threadIdx.x >> 6);
    int lane = threadIdx.x & 63;
    const float* xr = x + (size_t)wid * D_;
    float a0 = 0.f, a1 = 0.f, a2 = 0.f, a3 = 0.f;
    for (int i = lane; i < D_; i += 64) {
        float xv = xr[i];
        float4 w = reinterpret_cast<const float4*>(rw)[i];
        a0 += xv * w.x; a1 += xv * w.y; a2 += xv * w.z; a3 += xv * w.w;
    }
    for (int off = 32; off; off >>= 1) {
        a0 += __shfl_down(a0, off, 64);
        a1 += __shfl_down(a1, off, 64);
        a2 += __shfl_down(a2, off, 64);
        a3 += __shfl_down(a3, off, 64);
    }
    if (lane == 0) {
        float4 v; v.x = a0; v.y = a1; v.z = a2; v.w = a3;
        reinterpret_cast<float4*>(r)[wid] = v;
    }
}

__global__ void k_scan(float* __restrict__ r) {
    int b = blockIdx.x >> 2, e = blockIdx.x & 3;
    int lane = threadIdx.x;
    float carry = 0.f;
    for (int c = 0; c < S_ / 64; ++c) {
        int s = c * 64 + lane;
        float* p = r + ((size_t)(b * S_ + s)) * E_ + e;
        float v = *p;
        #pragma unroll
        for (int off = 1; off < 64; off <<= 1) {
            float u = __shfl_up(v, off, 64);
            if (lane >= off) v += u;
        }
        v += carry;
        *p = v;
        carry = __shfl(v, 63, 64);
    }
}

__global__ void k_route(const float* __restrict__ r, float* __restrict__ gate,
                        int* __restrict__ list, int* __restrict__ counts) {
    int t = blockIdx.x * blockDim.x + threadIdx.x;
    if (t >= T_) return;
    int s = t & (S_ - 1);
    float4 l4 = reinterpret_cast<const float4*>(r)[t];
    float inv = 1.f / (float)(s + 1);
    float l[4] = { l4.x * inv, l4.y * inv, l4.z * inv, l4.w * inv };
    int best = 0; float m = l[0];
    #pragma unroll
    for (int e = 1; e < 4; ++e) if (l[e] > m) { m = l[e]; best = e; }
    float sum = 0.f;
    #pragma unroll
    for (int e = 0; e < 4; ++e) sum += expf(l[e] - m);
    gate[t] = 1.f / sum;
    int pos = atomicAdd(&counts[best], 1);
    list[best * T_ + pos] = t;
}

__global__ void k_offs(const int* __restrict__ counts, int* __restrict__ offs,
                       int* __restrict__ pbase) {
    if (threadIdx.x == 0) {
        int a = 0, p = 0;
        pbase[0] = 0;
        for (int e = 0; e < E_; ++e) {
            offs[e] = a; a += counts[e];
            p += (counts[e] + 255) & ~255;
            pbase[e + 1] = p;
        }
    }
}

// ---------------- gather x into padded expert order, frag-tiled bf16 ----------------
__global__ __launch_bounds__(256)
void k_gather1(const float* __restrict__ x, const int* __restrict__ list,
               const int* __restrict__ counts, const int* __restrict__ pbase,
               ushort_t* __restrict__ Xb)
{
    constexpr int KB = D_ / 32;
    const int g = blockIdx.x;
    const int r15 = threadIdx.x & 15;
    const int kq = threadIdx.x >> 4;
    const int v = g * 16 + r15;
    int e = 0;
    #pragma unroll
    for (int i = 0; i < E_; ++i) if (v >= pbase[i + 1]) e = i + 1;
    int token = -1;
    if (e < E_) {
        int local = v - pbase[e];
        if (local < counts[e]) token = list[e * T_ + local];
    }
    const float* xr = x + (size_t)(token >= 0 ? token : 0) * D_;
    #pragma unroll
    for (int c8 = 0; c8 < 8; ++c8) {
        const int k = kq * 64 + c8 * 8;
        float vv[8];
        if (token >= 0) {
            float4 u0 = *reinterpret_cast<const float4*>(xr + k);
            float4 u1 = *reinterpret_cast<const float4*>(xr + k + 4);
            vv[0]=u0.x; vv[1]=u0.y; vv[2]=u0.z; vv[3]=u0.w;
            vv[4]=u1.x; vv[5]=u1.y; vv[6]=u1.z; vv[7]=u1.w;
        } else {
            #pragma unroll
            for (int j = 0; j < 8; ++j) vv[j] = 0.f;
        }
        unsigned hw[4];
        #pragma unroll
        for (int j = 0; j < 4; ++j)
            hw[j] = (unsigned)f2bf_rne(vv[2*j]) | ((unsigned)f2bf_rne(vv[2*j+1]) << 16);
        size_t off = (((size_t)g * KB + (k >> 5)) * 64 + ((k >> 3) & 3) * 16 + r15) * 8;
        *reinterpret_cast<uint4*>(Xb + off) = make_uint4(hw[0], hw[1], hw[2], hw[3]);
    }
}

// ---------------- weight conversion to frag-order bf16 plane ----------------
__global__ __launch_bounds__(256)
void k_convert_w1(const float* __restrict__ W, ushort_t* __restrict__ P,
                  int K, int N) {
    const int e = blockIdx.z;
    const int n0 = blockIdx.x * 128;
    const int k0 = blockIdx.y * 32;
    const int kb = blockIdx.y;
    const int NT = N >> 4, KB = K >> 5;
    __shared__ float lf[32 * 128];
    const float* We = W + (size_t)e * K * N;
    const int tid = threadIdx.x;
    #pragma unroll
    for (int i = 0; i < 4; ++i) {
        int q = i * 256 + tid;
        int k = q >> 5, c4 = q & 31;
        float4 v = *reinterpret_cast<const float4*>(We + (size_t)(k0 + k) * N + n0 + c4 * 4);
        *reinterpret_cast<float4*>(lf + k * 128 + c4 * 4) = v;
    }
    __syncthreads();
    #pragma unroll
    for (int p = 0; p < 2; ++p) {
        int q = p * 256 + tid;
        int n = q & 127, kg = q >> 7;
        unsigned hw[4];
        #pragma unroll
        for (int j = 0; j < 8; j += 2) {
            float f0 = lf[(kg * 8 + j) * 128 + n];
            float f1 = lf[(kg * 8 + j + 1) * 128 + n];
            hw[j >> 1] = (unsigned)f2bf_rne(f0) | ((unsigned)f2bf_rne(f1) << 16);
        }
        size_t off = ((((size_t)e * NT + ((n0 + n) >> 4)) * KB + kb) * 64
                      + (kg * 16 + (n & 15))) * 8;
        *reinterpret_cast<uint4*>(P + off) = make_uint4(hw[0], hw[1], hw[2], hw[3]);
    }
}

// ---------------- main grouped GEMMs: R17 body + 4 blocks/CU reg budget ----------------
// 128x128 tile, BK=32, 256 thr = 4 waves (2x2), wave tile 64x64, acc[4][4]=64 AGPR.
// __launch_bounds__(256, 4): cap 128 regs/thread (64 AGPR + <=64 VGPR) ->
// 4 waves/SIMD = 4 blocks/CU = 16 waves/CU (R17 got 136 regs -> only 2 blocks).
// LDS = 16KB single buffer. Per step: barrier -> 4 gload16/wave -> barrier ->
// 8 ds_read + 16 MFMA/wave. Minimum-traffic tile (1.18 GB/GEMM) at max residency.
// MODE 0: h = gelu(Xg @ w1 + b1), K=1024 (32 steps), grid (72 m, 32 n).
// MODE 1: out += gate*(h @ w2 [+b2]), K=4096 split 2x2048 (64 steps),
//         grid (72 m, 8 n, 2 kth), atomicAdd into zeroed out.
template<int MODE>
__global__ __launch_bounds__(256, 4)
void k_gL(const ushort_t* __restrict__ A, const ushort_t* __restrict__ Bw,
          const float* __restrict__ bias, float* __restrict__ outF,
          ushort_t* __restrict__ outH,
          const int* __restrict__ list, const int* __restrict__ counts,
          const int* __restrict__ pbase, const float* __restrict__ gate)
{
    constexpr int K    = (MODE == 0) ? D_ : F_;
    constexpr int N    = (MODE == 0) ? F_ : D_;
    constexpr int KSEG = (MODE == 0) ? K : K / 2;
    constexpr int STEPS = KSEG / 32;         // 32 or 64
    constexpr int KB32 = K / 32;
    constexpr int NT   = N / 16;
    constexpr int KBH  = F_ / 32;

    const int m0g = blockIdx.x * 128;
    if (m0g >= pbase[E_]) return;
    int e = 0;
    #pragma unroll
    for (int i = 1; i <= 3; ++i) if (m0g >= pbase[i]) e = i;
    const int cnt = counts[e];
    const int m0 = m0g - pbase[e];
    if (m0 >= cnt) return;                   // pure-pad block
    const int n0 = blockIdx.y * 128;
    const int kth = (MODE == 0) ? 0 : blockIdx.z;
    const int koff = kth * (KSEG / 32);

    const int tid = threadIdx.x, wid = tid >> 6, lane = tid & 63;
    const int l15 = lane & 15, lkg = lane >> 4;
    const int wr = wid >> 1, wc = wid & 1;   // 2x2 wave grid, wave tile 64x64
    const int G0 = m0g >> 4;

    // single 16KB buffer: A chunks 0-7 (row-groups), B chunks 8-15 (nt groups)
    __shared__ __align__(16) ushort_t lds[16 * 512];

    const ushort_t* aP[2]; const ushort_t* bP[2];
    #pragma unroll
    for (int j = 0; j < 2; ++j) {
        const int c = wid * 2 + j;           // 0..7
        aP[j] = A + ((size_t)(G0 + c) * KB32 + koff) * 512 + (size_t)lane * 8;
        bP[j] = Bw + (((size_t)e * NT + (n0 >> 4) + c) * KB32 + koff) * 512
                   + (size_t)lane * 8;
    }

    f32x4 acc[4][4];
    #pragma unroll
    for (int i = 0; i < 4; ++i)
        #pragma unroll
        for (int j = 0; j < 4; ++j) acc[i][j] = (f32x4){0.f, 0.f, 0.f, 0.f};

    for (int t = 0; t < STEPS; ++t) {
        __syncthreads();                     // prev compute's ds_reads done
        const size_t so = (size_t)t * 512;
        #pragma unroll
        for (int j = 0; j < 2; ++j) {
            gload16(aP[j] + so, &lds[(wid * 2 + j) * 512]);
            gload16(bP[j] + so, &lds[(8 + wid * 2 + j) * 512]);
        }
        __syncthreads();                     // implicit vmcnt(0): tile ready
        short8 av[4], bv[4];
        #pragma unroll
        for (int mi = 0; mi < 4; ++mi)
            av[mi] = *reinterpret_cast<const short8*>(
                &lds[(wr * 4 + mi) * 512 + lane * 8]);
        #pragma unroll
        for (int ni = 0; ni < 4; ++ni)
            bv[ni] = *reinterpret_cast<const short8*>(
                &lds[(8 + wc * 4 + ni) * 512 + lane * 8]);
        #pragma unroll
        for (int mi = 0; mi < 4; ++mi)
            #pragma unroll
            for (int ni = 0; ni < 4; ++ni)
                acc[mi][ni] = __builtin_amdgcn_mfma_f32_16x16x32_bf16(
                    av[mi], bv[ni], acc[mi][ni], 0, 0, 0);
    }

    const float* be = bias + (size_t)e * N;
    if (MODE == 0) {
        #pragma unroll
        for (int mi = 0; mi < 4; ++mi) {
            const int g2 = G0 + wr * 4 + mi;
            #pragma unroll
            for (int rg = 0; rg < 4; ++rg) {
                const int r15o = lkg * 4 + rg;
                #pragma unroll
                for (int ni = 0; ni < 4; ++ni) {
                    const int f = n0 + wc * 64 + ni * 16 + l15;
                    float v = acc[mi][ni][rg] + be[f];
                    float u = 1.5957691216057308f * (v + 0.044715f * v * v * v);
                    v = v / (1.f + __expf(-u));
                    size_t off = (((size_t)g2 * KBH + (f >> 5)) * 64
                                  + ((f >> 3) & 3) * 16 + r15o) * 8 + (f & 7);
                    outH[off] = f2bf_rne(v);
                }
            }
        }
    } else {
        const int* lst = list + (size_t)e * T_;
        #pragma unroll
        for (int mi = 0; mi < 4; ++mi) {
            #pragma unroll
            for (int rg = 0; rg < 4; ++rg) {
                int rm = m0 + wr * 64 + mi * 16 + lkg * 4 + rg;
                if (rm >= cnt) continue;
                int t = lst[rm];
                float gv = gate[t];
                float* crow = outF + (size_t)t * (size_t)N;
                #pragma unroll
                for (int ni = 0; ni < 4; ++ni) {
                    int col = n0 + wc * 64 + ni * 16 + l15;
                    float v = acc[mi][ni][rg] + (kth == 0 ? be[col] : 0.f);
                    atomicAdd(&crow[col], gv * v);
                }
            }
        }
    }
}

// ---------------- launch ----------------

extern "C" void kernel_launch(void* const* d_in, const int* in_sizes, int n_in,
                              void* d_out, int out_size, void* d_ws, size_t ws_size,
                              hipStream_t stream) {
    const float* x   = (const float*)d_in[0];
    const float* rw  = (const float*)d_in[1];
    const float* w1  = (const float*)d_in[2];
    const float* b1  = (const float*)d_in[3];
    const float* w2  = (const float*)d_in[4];
    const float* b2  = (const float*)d_in[5];
    float* out = (float*)d_out;

    const size_t HCAP = (size_t)PCAP_ * F_;
    const size_t XCAP = (size_t)PCAP_ * D_;
    const size_t WCAP = (size_t)E_ * D_ * F_;
    const size_t misc = ((size_t)T_ * E_ + T_ + (size_t)E_ * T_) * 4 + 256;
    const size_t need = (HCAP + XCAP + WCAP) * 2 + misc;

    if (ws_size < need) return;  // fail loudly

    ushort_t* hB = (ushort_t*)d_ws;
    ushort_t* xB = hB + HCAP;
    ushort_t* wB = xB + XCAP;
    float* r    = (float*)(wB + WCAP);
    float* gate = r + (size_t)T_ * E_;
    int* list   = (int*)(gate + T_);
    int* counts = list + (size_t)E_ * T_;
    int* offs   = counts + E_;
    int* pbase  = offs + E_;

    hipMemsetAsync(out, 0, (size_t)T_ * D_ * 4, stream);   // atomic-add target

    k_router<<<T_ / 4, 256, 0, stream>>>(x, rw, r, counts);
    k_convert_w1<<<dim3(F_ / 128, D_ / 32, E_), 256, 0, stream>>>(w1, wB, D_, F_);
    k_scan<<<B_ * E_, 64, 0, stream>>>(r);
    k_route<<<T_ / 256, 256, 0, stream>>>(r, gate, list, counts);
    k_offs<<<1, 64, 0, stream>>>(counts, offs, pbase);
    k_gather1<<<GCAP_, 256, 0, stream>>>(x, list, counts, pbase, xB);

    // m-fastest compact grids, 128-row tiles
    k_gL<0><<<dim3(MB128_, F_ / 128), 256, 0, stream>>>(
        xB, wB, b1, nullptr, hB, list, counts, pbase, nullptr);
    k_convert_w1<<<dim3(D_ / 128, F_ / 32, E_), 256, 0, stream>>>(w2, wB, F_, D_);
    k_gL<1><<<dim3(MB128_, D_ / 128, 2), 256, 0, stream>>>(
        hB, wB, b2, out, nullptr, list, counts, pbase, gate);
}

// Round 22
// 357.976 us; speedup vs baseline: 1.2365x; 1.2365x over previous
//
#include <hip/hip_runtime.h>
#include <math.h>

#define B_ 4
#define S_ 2048
#define D_ 1024
#define F_ 4096
#define E_ 4
#define T_ (B_*S_)        // 8192 tokens
#define PCAP_ 9216        // max padded rows (256-pad per expert)
#define GCAP_ (PCAP_/16)  // 576 row-groups
#define MB128_ (PCAP_/128) // 72 global m-blocks at 128-row tiles

typedef unsigned short ushort_t;
typedef __attribute__((ext_vector_type(8))) short short8;
typedef __attribute__((ext_vector_type(4))) float f32x4;

__device__ __forceinline__ ushort_t f2bf_rne(float f) {
    unsigned u = __float_as_uint(f);
    unsigned r = 0x7FFFu + ((u >> 16) & 1u);
    u += r;
    return (ushort_t)(u >> 16);
}

__device__ __forceinline__ void gload16(const void* g, void* l) {
    __builtin_amdgcn_global_load_lds(
        (const __attribute__((address_space(1))) unsigned int*)g,
        (__attribute__((address_space(3))) unsigned int*)l, 16, 0, 0);
}

// ---------------- routing ----------------

__global__ void k_router(const float* __restrict__ x, const float* __restrict__ rw,
                         float* __restrict__ r, int* __restrict__ counts) {
    if (blockIdx.x == 0 && threadIdx.x < E_) counts[threadIdx.x] = 0;
    int wid = blockIdx.x * 4 + (threadIdx.x >> 6);
    int lane = threadIdx.x & 63;
    const float* xr = x + (size_t)wid * D_;
    float a0 = 0.f, a1 = 0.f, a2 = 0.f, a3 = 0.f;
    for (int i = lane; i < D_; i += 64) {
        float xv = xr[i];
        float4 w = reinterpret_cast<const float4*>(rw)[i];
        a0 += xv * w.x; a1 += xv * w.y; a2 += xv * w.z; a3 += xv * w.w;
    }
    for (int off = 32; off; off >>= 1) {
        a0 += __shfl_down(a0, off, 64);
        a1 += __shfl_down(a1, off, 64);
        a2 += __shfl_down(a2, off, 64);
        a3 += __shfl_down(a3, off, 64);
    }
    if (lane == 0) {
        float4 v; v.x = a0; v.y = a1; v.z = a2; v.w = a3;
        reinterpret_cast<float4*>(r)[wid] = v;
    }
}

__global__ void k_scan(float* __restrict__ r) {
    int b = blockIdx.x >> 2, e = blockIdx.x & 3;
    int lane = threadIdx.x;
    float carry = 0.f;
    for (int c = 0; c < S_ / 64; ++c) {
        int s = c * 64 + lane;
        float* p = r + ((size_t)(b * S_ + s)) * E_ + e;
        float v = *p;
        #pragma unroll
        for (int off = 1; off < 64; off <<= 1) {
            float u = __shfl_up(v, off, 64);
            if (lane >= off) v += u;
        }
        v += carry;
        *p = v;
        carry = __shfl(v, 63, 64);
    }
}

__global__ void k_route(const float* __restrict__ r, float* __restrict__ gate,
                        int* __restrict__ list, int* __restrict__ counts) {
    int t = blockIdx.x * blockDim.x + threadIdx.x;
    if (t >= T_) return;
    int s = t & (S_ - 1);
    float4 l4 = reinterpret_cast<const float4*>(r)[t];
    float inv = 1.f / (float)(s + 1);
    float l[4] = { l4.x * inv, l4.y * inv, l4.z * inv, l4.w * inv };
    int best = 0; float m = l[0];
    #pragma unroll
    for (int e = 1; e < 4; ++e) if (l[e] > m) { m = l[e]; best = e; }
    float sum = 0.f;
    #pragma unroll
    for (int e = 0; e < 4; ++e) sum += expf(l[e] - m);
    gate[t] = 1.f / sum;
    int pos = atomicAdd(&counts[best], 1);
    list[best * T_ + pos] = t;
}

__global__ void k_offs(const int* __restrict__ counts, int* __restrict__ offs,
                       int* __restrict__ pbase) {
    if (threadIdx.x == 0) {
        int a = 0, p = 0;
        pbase[0] = 0;
        for (int e = 0; e < E_; ++e) {
            offs[e] = a; a += counts[e];
            p += (counts[e] + 255) & ~255;
            pbase[e + 1] = p;
        }
    }
}

// ---------------- gather x into padded expert order, frag-tiled bf16 ----------------
__global__ __launch_bounds__(256)
void k_gather1(const float* __restrict__ x, const int* __restrict__ list,
               const int* __restrict__ counts, const int* __restrict__ pbase,
               ushort_t* __restrict__ Xb)
{
    constexpr int KB = D_ / 32;
    const int g = blockIdx.x;
    const int r15 = threadIdx.x & 15;
    const int kq = threadIdx.x >> 4;
    const int v = g * 16 + r15;
    int e = 0;
    #pragma unroll
    for (int i = 0; i < E_; ++i) if (v >= pbase[i + 1]) e = i + 1;
    int token = -1;
    if (e < E_) {
        int local = v - pbase[e];
        if (local < counts[e]) token = list[e * T_ + local];
    }
    const float* xr = x + (size_t)(token >= 0 ? token : 0) * D_;
    #pragma unroll
    for (int c8 = 0; c8 < 8; ++c8) {
        const int k = kq * 64 + c8 * 8;
        float vv[8];
        if (token >= 0) {
            float4 u0 = *reinterpret_cast<const float4*>(xr + k);
            float4 u1 = *reinterpret_cast<const float4*>(xr + k + 4);
            vv[0]=u0.x; vv[1]=u0.y; vv[2]=u0.z; vv[3]=u0.w;
            vv[4]=u1.x; vv[5]=u1.y; vv[6]=u1.z; vv[7]=u1.w;
        } else {
            #pragma unroll
            for (int j = 0; j < 8; ++j) vv[j] = 0.f;
        }
        unsigned hw[4];
        #pragma unroll
        for (int j = 0; j < 4; ++j)
            hw[j] = (unsigned)f2bf_rne(vv[2*j]) | ((unsigned)f2bf_rne(vv[2*j+1]) << 16);
        size_t off = (((size_t)g * KB + (k >> 5)) * 64 + ((k >> 3) & 3) * 16 + r15) * 8;
        *reinterpret_cast<uint4*>(Xb + off) = make_uint4(hw[0], hw[1], hw[2], hw[3]);
    }
}

// ---------------- weight conversion to frag-order bf16 plane ----------------
__global__ __launch_bounds__(256)
void k_convert_w1(const float* __restrict__ W, ushort_t* __restrict__ P,
                  int K, int N) {
    const int e = blockIdx.z;
    const int n0 = blockIdx.x * 128;
    const int k0 = blockIdx.y * 32;
    const int kb = blockIdx.y;
    const int NT = N >> 4, KB = K >> 5;
    __shared__ float lf[32 * 128];
    const float* We = W + (size_t)e * K * N;
    const int tid = threadIdx.x;
    #pragma unroll
    for (int i = 0; i < 4; ++i) {
        int q = i * 256 + tid;
        int k = q >> 5, c4 = q & 31;
        float4 v = *reinterpret_cast<const float4*>(We + (size_t)(k0 + k) * N + n0 + c4 * 4);
        *reinterpret_cast<float4*>(lf + k * 128 + c4 * 4) = v;
    }
    __syncthreads();
    #pragma unroll
    for (int p = 0; p < 2; ++p) {
        int q = p * 256 + tid;
        int n = q & 127, kg = q >> 7;
        unsigned hw[4];
        #pragma unroll
        for (int j = 0; j < 8; j += 2) {
            float f0 = lf[(kg * 8 + j) * 128 + n];
            float f1 = lf[(kg * 8 + j + 1) * 128 + n];
            hw[j >> 1] = (unsigned)f2bf_rne(f0) | ((unsigned)f2bf_rne(f1) << 16);
        }
        size_t off = ((((size_t)e * NT + ((n0 + n) >> 4)) * KB + kb) * 64
                      + (kg * 16 + (n & 15))) * 8;
        *reinterpret_cast<uint4*>(P + off) = make_uint4(hw[0], hw[1], hw[2], hw[3]);
    }
}

// ---------------- main grouped GEMMs: R18 champion (thin waves, 16KB single buf) ----
// 128x128 tile, BK=32, 512 thr = 8 waves (2M x 4N), wave tile 64x32,
// acc[4][2] = 32 AGPR (~40 VGPR) -> 2 blocks/CU = 16 waves/CU.
// LDS = 16KB single buffer (A chunks 0-7, B chunks 8-15).
// Per step: barrier -> 2 gload16/wave -> barrier -> 6 ds_read + 8 MFMA/wave.
// MODE 0: h = gelu(Xg @ w1 + b1), K=1024 (32 steps), grid (72 m, 32 n).
// MODE 1: out = gate*(h @ w2 + b2), K=4096 (128 steps), grid (72 m, 8 n),
//         DIRECT store (no split-K, no memset, no atomics).
template<int MODE>
__global__ __launch_bounds__(512)
void k_gM(const ushort_t* __restrict__ A, const ushort_t* __restrict__ Bw,
          const float* __restrict__ bias, float* __restrict__ outF,
          ushort_t* __restrict__ outH,
          const int* __restrict__ list, const int* __restrict__ counts,
          const int* __restrict__ pbase, const float* __restrict__ gate)
{
    constexpr int K    = (MODE == 0) ? D_ : F_;
    constexpr int N    = (MODE == 0) ? F_ : D_;
    constexpr int STEPS = K / 32;            // 32 or 128
    constexpr int KB32 = K / 32;
    constexpr int NT   = N / 16;
    constexpr int KBH  = F_ / 32;

    const int m0g = blockIdx.x * 128;
    if (m0g >= pbase[E_]) return;
    int e = 0;
    #pragma unroll
    for (int i = 1; i <= 3; ++i) if (m0g >= pbase[i]) e = i;
    const int cnt = counts[e];
    const int m0 = m0g - pbase[e];
    if (m0 >= cnt) return;                   // pure-pad block
    const int n0 = blockIdx.y * 128;

    const int tid = threadIdx.x, wid = tid >> 6, lane = tid & 63;
    const int l15 = lane & 15, lkg = lane >> 4;
    const int wr = wid >> 2, wc = wid & 3;   // 2M x 4N, wave tile 64x32
    const int G0 = m0g >> 4;

    // single 16KB buffer: A chunks 0-7 (row-groups), B chunks 8-15 (nt groups)
    __shared__ __align__(16) ushort_t lds[16 * 512];

    // per-wave staging: 1 A chunk (wid) + 1 B chunk (8+wid)
    const ushort_t* aP = A + ((size_t)(G0 + wid) * KB32) * 512 + (size_t)lane * 8;
    const ushort_t* bP = Bw + (((size_t)e * NT + (n0 >> 4) + wid) * KB32) * 512
                            + (size_t)lane * 8;

    f32x4 acc[4][2];
    #pragma unroll
    for (int i = 0; i < 4; ++i)
        #pragma unroll
        for (int j = 0; j < 2; ++j) acc[i][j] = (f32x4){0.f, 0.f, 0.f, 0.f};

    for (int t = 0; t < STEPS; ++t) {
        __syncthreads();                     // prev compute's ds_reads done
        const size_t so = (size_t)t * 512;
        gload16(aP + so, &lds[wid * 512]);
        gload16(bP + so, &lds[(8 + wid) * 512]);
        __syncthreads();                     // implicit vmcnt(0): tile ready
        short8 av[4], bv[2];
        #pragma unroll
        for (int mi = 0; mi < 4; ++mi)
            av[mi] = *reinterpret_cast<const short8*>(
                &lds[(wr * 4 + mi) * 512 + lane * 8]);
        #pragma unroll
        for (int ni = 0; ni < 2; ++ni)
            bv[ni] = *reinterpret_cast<const short8*>(
                &lds[(8 + wc * 2 + ni) * 512 + lane * 8]);
        #pragma unroll
        for (int mi = 0; mi < 4; ++mi)
            #pragma unroll
            for (int ni = 0; ni < 2; ++ni)
                acc[mi][ni] = __builtin_amdgcn_mfma_f32_16x16x32_bf16(
                    av[mi], bv[ni], acc[mi][ni], 0, 0, 0);
    }

    const float* be = bias + (size_t)e * N;
    if (MODE == 0) {
        #pragma unroll
        for (int mi = 0; mi < 4; ++mi) {
            const int g2 = G0 + wr * 4 + mi;
            #pragma unroll
            for (int rg = 0; rg < 4; ++rg) {
                const int r15o = lkg * 4 + rg;
                #pragma unroll
                for (int ni = 0; ni < 2; ++ni) {
                    const int f = n0 + wc * 32 + ni * 16 + l15;
                    float v = acc[mi][ni][rg] + be[f];
                    float u = 1.5957691216057308f * (v + 0.044715f * v * v * v);
                    v = v / (1.f + __expf(-u));
                    size_t off = (((size_t)g2 * KBH + (f >> 5)) * 64
                                  + ((f >> 3) & 3) * 16 + r15o) * 8 + (f & 7);
                    outH[off] = f2bf_rne(v);
                }
            }
        }
    } else {
        const int* lst = list + (size_t)e * T_;
        #pragma unroll
        for (int mi = 0; mi < 4; ++mi) {
            #pragma unroll
            for (int rg = 0; rg < 4; ++rg) {
                int rm = m0 + wr * 64 + mi * 16 + lkg * 4 + rg;
                if (rm >= cnt) continue;
                int t = lst[rm];
                float gv = gate[t];
                float* crow = outF + (size_t)t * (size_t)N;
                #pragma unroll
                for (int ni = 0; ni < 2; ++ni) {
                    int col = n0 + wc * 32 + ni * 16 + l15;
                    crow[col] = gv * (acc[mi][ni][rg] + be[col]);
                }
            }
        }
    }
}

// ---------------- launch ----------------

extern "C" void kernel_launch(void* const* d_in, const int* in_sizes, int n_in,
                              void* d_out, int out_size, void* d_ws, size_t ws_size,
                              hipStream_t stream) {
    const float* x   = (const float*)d_in[0];
    const float* rw  = (const float*)d_in[1];
    const float* w1  = (const float*)d_in[2];
    const float* b1  = (const float*)d_in[3];
    const float* w2  = (const float*)d_in[4];
    const float* b2  = (const float*)d_in[5];
    float* out = (float*)d_out;

    const size_t HCAP = (size_t)PCAP_ * F_;
    const size_t XCAP = (size_t)PCAP_ * D_;
    const size_t WCAP = (size_t)E_ * D_ * F_;
    const size_t misc = ((size_t)T_ * E_ + T_ + (size_t)E_ * T_) * 4 + 256;
    const size_t need = (HCAP + XCAP + WCAP) * 2 + misc;

    if (ws_size < need) return;  // fail loudly

    ushort_t* hB = (ushort_t*)d_ws;
    ushort_t* xB = hB + HCAP;
    ushort_t* wB = xB + XCAP;
    float* r    = (float*)(wB + WCAP);
    float* gate = r + (size_t)T_ * E_;
    int* list   = (int*)(gate + T_);
    int* counts = list + (size_t)E_ * T_;
    int* offs   = counts + E_;
    int* pbase  = offs + E_;

    k_router<<<T_ / 4, 256, 0, stream>>>(x, rw, r, counts);
    k_convert_w1<<<dim3(F_ / 128, D_ / 32, E_), 256, 0, stream>>>(w1, wB, D_, F_);
    k_scan<<<B_ * E_, 64, 0, stream>>>(r);
    k_route<<<T_ / 256, 256, 0, stream>>>(r, gate, list, counts);
    k_offs<<<1, 64, 0, stream>>>(counts, offs, pbase);
    k_gather1<<<GCAP_, 256, 0, stream>>>(x, list, counts, pbase, xB);

    // m-fastest compact grids, 128-row tiles
    k_gM<0><<<dim3(MB128_, F_ / 128), 512, 0, stream>>>(
        xB, wB, b1, nullptr, hB, list, counts, pbase, nullptr);
    k_convert_w1<<<dim3(D_ / 128, F_ / 32, E_), 256, 0, stream>>>(w2, wB, F_, D_);
    k_gM<1><<<dim3(MB128_, D_ / 128), 512, 0, stream>>>(
        hB, wB, b2, out, nullptr, list, counts, pbase, gate);
}